// Round 3
// baseline (556.567 us; speedup 1.0000x reference)
//
#include <hip/hip_runtime.h>
#include <math.h>

#define B_   16
#define S_   4096
#define D_   768
#define H_   384
#define NTOK (B_ * S_)
#define KTOP 40
#define NTILES 24          // 384/16 n-tiles
#define KCH    24          // 768/32 k-chunks

typedef __attribute__((ext_vector_type(8))) short bf16x8;
typedef __attribute__((ext_vector_type(4))) float f32x4;

static __device__ __forceinline__ unsigned short f2bf_rne(float x) {
    union { float f; unsigned u; } v; v.f = x;
    unsigned r = v.u + 0x7FFFu + ((v.u >> 16) & 1u);   // RNE
    return (unsigned short)(r >> 16);
}
static __device__ __forceinline__ float bf2f(unsigned short h) {
    union { unsigned u; float f; } v; v.u = ((unsigned)h) << 16; return v.f;
}

// truncation split: hi = top-16-bits of f32 (exact trunc), lo = RNE(residual)
// dropped al*bl term <= 2^-17 relative -- negligible vs fp32 reference noise.
static __device__ __forceinline__ void splitA(const float4 v0, const float4 v1,
                                              bf16x8* hi, bf16x8* lo) {
    float v[8] = {v0.x, v0.y, v0.z, v0.w, v1.x, v1.y, v1.z, v1.w};
    bf16x8 h, l;
#pragma unroll
    for (int j = 0; j < 8; ++j) {
        union { float f; unsigned u; } a; a.f = v[j];
        const unsigned hu = a.u & 0xFFFF0000u;
        union { unsigned u; float f; } hf; hf.u = hu;
        const float r = v[j] - hf.f;
        h[j] = (short)(a.u >> 16);
        l[j] = (short)f2bf_rne(r);
    }
    *hi = h; *lo = l;
}

// ---------------------------------------------------------------------------
// Kernel 0: pack W1 into MFMA B-fragment layout, bf16 hi/lo, CHUNK-MAJOR:
// frag element j of lane: B[k = ch*32 + (lane>>4)*8 + j][n = nt*16 + (lane&15)]
// stored at ((ch*24 + nt)*64 + lane)*8 + j
// ---------------------------------------------------------------------------
__global__ __launch_bounds__(64) void pack_w1(const float* __restrict__ W1,
                                              unsigned short* __restrict__ bh,
                                              unsigned short* __restrict__ bl)
{
    const int nt   = blockIdx.x;        // 0..23
    const int ch   = blockIdx.y;        // 0..23
    const int lane = threadIdx.x;
    const int n    = nt * 16 + (lane & 15);
    const int k0   = ch * 32 + (lane >> 4) * 8;

    unsigned short h8[8], l8[8];
#pragma unroll
    for (int j = 0; j < 8; ++j) {
        const float v = W1[(size_t)(k0 + j) * H_ + n];
        const unsigned short h = f2bf_rne(v);
        h8[j] = h;
        l8[j] = f2bf_rne(v - bf2f(h));
    }
    const size_t base = ((size_t)(ch * NTILES + nt) * 64 + lane) * 8;
#pragma unroll
    for (int j = 0; j < 8; ++j) { bh[base + j] = h8[j]; bl[base + j] = l8[j]; }
}

// ---------------------------------------------------------------------------
// Kernel 1: fused scores. Block = 64 tokens x 384 cols, 4 waves; wave w owns
// n-tiles w*6..w*6+5, all 64 rows. NO LDS staging, NO K-loop barriers:
// A fragments loaded straight from global (L1-cached, 4-way wave reuse) and
// split to bf16 hi/lo in registers; B fragments rolling register prefetch.
// ---------------------------------------------------------------------------
__global__ __launch_bounds__(256) void score_kernel(
    const float* __restrict__ features,
    const unsigned short* __restrict__ bh_g,
    const unsigned short* __restrict__ bl_g,
    const float* __restrict__ b1,
    const float* __restrict__ gamma,
    const float* __restrict__ beta,
    const float* __restrict__ W2,
    const float* __restrict__ b2,
    float* __restrict__ scores)
{
    __shared__ float red[4][64];
    __shared__ float mu_s[64];
    __shared__ float rs_s[64];

    const int tid  = threadIdx.x;
    const int lane = tid & 63;
    const int w    = tid >> 6;
    const int base = blockIdx.x * 64;
    const int cl   = lane & 15;
    const int p    = lane >> 4;

    f32x4 acc[4][6];
#pragma unroll
    for (int m = 0; m < 4; ++m)
#pragma unroll
        for (int t = 0; t < 6; ++t) acc[m][t] = (f32x4){0.f, 0.f, 0.f, 0.f};

    // per-m A row pointers: lane (cl,p) consumes row m*16+cl, k in [c*32+p*8, +8)
    const float* pA[4];
#pragma unroll
    for (int m = 0; m < 4; ++m)
        pA[m] = features + (size_t)(base + m * 16 + cl) * D_ + p * 8;

    // B lane bases (chunk-major packed layout)
    const unsigned short* pbh = bh_g + (size_t)(w * 6) * 512 + (size_t)lane * 8;
    const unsigned short* pbl = bl_g + (size_t)(w * 6) * 512 + (size_t)lane * 8;

    // preload raw A chunk 0
    float4 ra[4][2];
#pragma unroll
    for (int m = 0; m < 4; ++m) {
        ra[m][0] = *(const float4*)(pA[m]);
        ra[m][1] = *(const float4*)(pA[m] + 4);
    }
    // preload B frag (c=0, t=0)
    bf16x8 bhB[2], blB[2];
    bhB[0] = *(const bf16x8*)(pbh);
    blB[0] = *(const bf16x8*)(pbl);

    size_t cOff = 0;                       // = c * 24*512 elements
    for (int c = 0; c < KCH; ++c, cOff += (size_t)NTILES * 512) {
        // convert current raw A -> fragments
        bf16x8 ahf[4], alf[4];
#pragma unroll
        for (int m = 0; m < 4; ++m) splitA(ra[m][0], ra[m][1], &ahf[m], &alf[m]);

        // prefetch raw A for next chunk (no barrier anywhere -> stays in flight)
        if (c + 1 < KCH) {
            const int d0 = (c + 1) * 32;
#pragma unroll
            for (int m = 0; m < 4; ++m) {
                ra[m][0] = *(const float4*)(pA[m] + d0);
                ra[m][1] = *(const float4*)(pA[m] + d0 + 4);
            }
        }

#pragma unroll
        for (int t = 0; t < 6; ++t) {
            const int cur = t & 1, nxt = cur ^ 1;
            // rolling B prefetch: next tile, or next chunk's tile 0
            if (t < 5) {
                bhB[nxt] = *(const bf16x8*)(pbh + cOff + (t + 1) * 512);
                blB[nxt] = *(const bf16x8*)(pbl + cOff + (t + 1) * 512);
            } else if (c + 1 < KCH) {
                bhB[nxt] = *(const bf16x8*)(pbh + cOff + (size_t)NTILES * 512);
                blB[nxt] = *(const bf16x8*)(pbl + cOff + (size_t)NTILES * 512);
            }
#pragma unroll
            for (int m = 0; m < 4; ++m)
                acc[m][t] = __builtin_amdgcn_mfma_f32_16x16x32_bf16(ahf[m], bhB[cur], acc[m][t], 0, 0, 0);
#pragma unroll
            for (int m = 0; m < 4; ++m)
                acc[m][t] = __builtin_amdgcn_mfma_f32_16x16x32_bf16(alf[m], bhB[cur], acc[m][t], 0, 0, 0);
#pragma unroll
            for (int m = 0; m < 4; ++m)
                acc[m][t] = __builtin_amdgcn_mfma_f32_16x16x32_bf16(ahf[m], blB[cur], acc[m][t], 0, 0, 0);
        }
    }

    // ---- epilogue (verified in round 2) ----
    float b1v[6], gv[6], bev[6], w2v[6];
#pragma unroll
    for (int t = 0; t < 6; ++t) {
        const int n = (w * 6 + t) * 16 + cl;
        b1v[t] = b1[n]; gv[t] = gamma[n]; bev[t] = beta[n]; w2v[t] = W2[n];
    }
#pragma unroll
    for (int m = 0; m < 4; ++m)
#pragma unroll
        for (int t = 0; t < 6; ++t)
#pragma unroll
            for (int r = 0; r < 4; ++r) acc[m][t][r] += b1v[t];

#pragma unroll
    for (int m = 0; m < 4; ++m) {
        float sm[4] = {0.f, 0.f, 0.f, 0.f};
#pragma unroll
        for (int t = 0; t < 6; ++t)
#pragma unroll
            for (int r = 0; r < 4; ++r) sm[r] += acc[m][t][r];
#pragma unroll
        for (int r = 0; r < 4; ++r) {
#pragma unroll
            for (int off = 1; off <= 8; off <<= 1) sm[r] += __shfl_xor(sm[r], off, 64);
        }
        if (cl == 0) {
#pragma unroll
            for (int r = 0; r < 4; ++r) red[w][m * 16 + p * 4 + r] = sm[r];
        }
    }
    __syncthreads();
    if (tid < 64) mu_s[tid] = (red[0][tid] + red[1][tid] + red[2][tid] + red[3][tid]) * (1.0f / H_);
    __syncthreads();

#pragma unroll
    for (int m = 0; m < 4; ++m) {
        float mur[4];
#pragma unroll
        for (int r = 0; r < 4; ++r) mur[r] = mu_s[m * 16 + p * 4 + r];
        float sm[4] = {0.f, 0.f, 0.f, 0.f};
#pragma unroll
        for (int t = 0; t < 6; ++t)
#pragma unroll
            for (int r = 0; r < 4; ++r) { const float d = acc[m][t][r] - mur[r]; sm[r] += d * d; }
#pragma unroll
        for (int r = 0; r < 4; ++r) {
#pragma unroll
            for (int off = 1; off <= 8; off <<= 1) sm[r] += __shfl_xor(sm[r], off, 64);
        }
        if (cl == 0) {
#pragma unroll
            for (int r = 0; r < 4; ++r) red[w][m * 16 + p * 4 + r] = sm[r];
        }
    }
    __syncthreads();
    if (tid < 64) rs_s[tid] = rsqrtf((red[0][tid] + red[1][tid] + red[2][tid] + red[3][tid]) * (1.0f / H_) + 1e-5f);
    __syncthreads();

#pragma unroll
    for (int m = 0; m < 4; ++m) {
        float mur[4], rsr[4];
#pragma unroll
        for (int r = 0; r < 4; ++r) { mur[r] = mu_s[m * 16 + p * 4 + r]; rsr[r] = rs_s[m * 16 + p * 4 + r]; }
        float sm[4] = {0.f, 0.f, 0.f, 0.f};
#pragma unroll
        for (int t = 0; t < 6; ++t)
#pragma unroll
            for (int r = 0; r < 4; ++r) {
                const float y  = (acc[m][t][r] - mur[r]) * rsr[r] * gv[t] + bev[t];
                const float ge = 0.5f * y * (1.0f + erff(y * 0.70710678118654752f));
                sm[r] = fmaf(ge, w2v[t], sm[r]);
            }
#pragma unroll
        for (int r = 0; r < 4; ++r) {
#pragma unroll
            for (int off = 1; off <= 8; off <<= 1) sm[r] += __shfl_xor(sm[r], off, 64);
        }
        if (cl == 0) {
#pragma unroll
            for (int r = 0; r < 4; ++r) red[w][m * 16 + p * 4 + r] = sm[r];
        }
    }
    __syncthreads();
    if (tid < 64) {
        const float s = red[0][tid] + red[1][tid] + red[2][tid] + red[3][tid] + b2[0];
        scores[base + tid] = 1.0f / (1.0f + expf(-s));
    }
}

// ---------------------------------------------------------------------------
// Kernel 2: per-batch exact top-40 via byte-wise radix select on float bits.
// Serial 256-bin scan replaced by parallel suffix-scan.
// ---------------------------------------------------------------------------
__global__ __launch_bounds__(256) void select_kernel(const float* __restrict__ scores,
                                                     int* __restrict__ sel)
{
    __shared__ unsigned int bits_s[S_];     // 16 KB
    __shared__ unsigned int hist[256];
    __shared__ int sufx[256];
    __shared__ int s_byte, s_rem;
    __shared__ unsigned int s_ngt, s_neq;
    __shared__ unsigned int candV[64];
    __shared__ int candI[64];
    __shared__ int eqI[256];

    const int b   = blockIdx.x;
    const int tid = threadIdx.x;

    for (int i = tid; i < S_; i += 256)
        bits_s[i] = __float_as_uint(scores[b * S_ + i]);
    if (tid == 0) { s_rem = KTOP; s_ngt = 0u; s_neq = 0u; }

    unsigned int prefix = 0u, mask = 0u;
    for (int pb = 3; pb >= 0; --pb) {
        hist[tid] = 0u;
        __syncthreads();
        for (int i = tid; i < S_; i += 256) {
            const unsigned int u = bits_s[i];
            if ((u & mask) == prefix) atomicAdd(&hist[(u >> (8 * pb)) & 255u], 1u);
        }
        __syncthreads();
        sufx[tid] = (int)hist[tid];
        __syncthreads();
        // suffix sum: sufx[i] = sum_{j>=i} hist[j]
        for (int st = 1; st < 256; st <<= 1) {
            const int v = (tid + st < 256) ? sufx[tid + st] : 0;
            __syncthreads();
            sufx[tid] += v;
            __syncthreads();
        }
        const int rem = s_rem;
        __syncthreads();
        if (sufx[tid] >= rem && (tid == 255 || sufx[tid + 1] < rem)) {
            s_byte = tid;
            s_rem  = rem - ((tid == 255) ? 0 : sufx[tid + 1]);
        }
        __syncthreads();
        prefix |= ((unsigned int)s_byte) << (8 * pb);
        mask   |= 0xFFu << (8 * pb);
        __syncthreads();
    }
    const unsigned int T = prefix;
    const int need = s_rem;                 // #ties at T to keep (>=1)

    for (int i = tid; i < S_; i += 256) {
        const unsigned int u = bits_s[i];
        if (u > T) {
            const unsigned int pos = atomicAdd(&s_ngt, 1u);
            candV[pos] = u; candI[pos] = i;          // n_gt <= 39 guaranteed
        } else if (u == T) {
            const unsigned int pos = atomicAdd(&s_neq, 1u);
            if (pos < 256u) eqI[pos] = i;
        }
    }
    __syncthreads();
    const int ngt = (int)s_ngt;
    const int neq = (int)(s_neq < 256u ? s_neq : 256u);
    for (int j = tid; j < neq; j += 256) {
        int rank = 0;
        for (int l = 0; l < neq; ++l) rank += (eqI[l] < eqI[j]) ? 1 : 0;
        if (rank < need) { candV[ngt + rank] = T; candI[ngt + rank] = eqI[j]; }
    }
    __syncthreads();
    if (tid < KTOP) {
        const unsigned int u = candV[tid];
        const int idx = candI[tid];
        int rank = 0;
        for (int j = 0; j < KTOP; ++j)
            rank += (candV[j] > u || (candV[j] == u && candI[j] < idx)) ? 1 : 0;
        sel[b * KTOP + rank] = idx;
    }
}

// ---------------------------------------------------------------------------
// Kernel 3: gather selected rows + write indices (as float). Grid (40,16).
// ---------------------------------------------------------------------------
__global__ __launch_bounds__(192) void gather_kernel(const float* __restrict__ features,
                                                     const int* __restrict__ sel,
                                                     float* __restrict__ out_tok,
                                                     float* __restrict__ out_idx)
{
    const int i = blockIdx.x;   // 0..39
    const int b = blockIdx.y;   // 0..15
    const int idx = sel[b * KTOP + i];
    const float4* src = (const float4*)(features + ((size_t)b * S_ + idx) * D_);
    float4* dst = (float4*)(out_tok + ((size_t)b * KTOP + i) * D_);
    dst[threadIdx.x] = src[threadIdx.x];
    if (threadIdx.x == 0) out_idx[b * KTOP + i] = (float)idx;
}

// ---------------------------------------------------------------------------
extern "C" void kernel_launch(void* const* d_in, const int* in_sizes, int n_in,
                              void* d_out, int out_size, void* d_ws, size_t ws_size,
                              hipStream_t stream)
{
    const float* features = (const float*)d_in[0];
    const float* W1       = (const float*)d_in[1];
    const float* b1       = (const float*)d_in[2];
    const float* gamma    = (const float*)d_in[3];
    const float* beta     = (const float*)d_in[4];
    const float* W2       = (const float*)d_in[5];
    const float* b2       = (const float*)d_in[6];

    unsigned short* bh = (unsigned short*)d_ws;            // 576 KB
    unsigned short* bl = bh + (size_t)D_ * H_;             // 576 KB
    float* scores      = (float*)(bl + (size_t)D_ * H_);   // 256 KB
    int*   sel         = (int*)(scores + NTOK);            // 2.5 KB

    float* out        = (float*)d_out;
    float* out_tokens = out;                               // [16,40,768]
    float* out_idx    = out + (size_t)B_ * KTOP * D_;      // [16,40]

    pack_w1<<<dim3(NTILES, KCH), 64, 0, stream>>>(W1, bh, bl);
    score_kernel<<<NTOK / 64, 256, 0, stream>>>(features, bh, bl, b1, gamma, beta, W2, b2, scores);
    select_kernel<<<B_, 256, 0, stream>>>(scores, sel);
    gather_kernel<<<dim3(KTOP, B_), 192, 0, stream>>>(features, sel, out_tokens, out_idx);
}